// Round 1
// baseline (307.866 us; speedup 1.0000x reference)
//
#include <hip/hip_runtime.h>
#include <hip/hip_bf16.h>

#define AS1 __attribute__((address_space(1)))
#define AS3 __attribute__((address_space(3)))

typedef __bf16 bf16x8_t __attribute__((ext_vector_type(8)));
typedef float f32x4_t __attribute__((ext_vector_type(4)));
typedef unsigned short ushort_t;
typedef unsigned int uint_t;

static __device__ __forceinline__ ushort_t f2b(float f) {
    __hip_bfloat16 h = __float2bfloat16(f);
    return __builtin_bit_cast(unsigned short, h);
}
static __device__ __forceinline__ float b2f(ushort_t u) {
    return __uint_as_float((uint_t)u << 16);
}

// ---------------------------------------------------------------- fused casts (one launch)
struct CastArgs {
    const float* src[5];
    ushort_t* dst[5];
    int cum[6];   // prefix sums of float4-group counts
};

__global__ __launch_bounds__(256) void cast_all(CastArgs a) {
    const int i = blockIdx.x * 256 + threadIdx.x;
    if (i >= a.cum[5]) return;
    int s = 0;
#pragma unroll
    for (int k = 1; k < 5; ++k) s += (i >= a.cum[k]);
    const int idx = i - a.cum[s];
    float4 v = ((const float4*)a.src[s])[idx];
    ushort4 o;
    o.x = f2b(v.x); o.y = f2b(v.y); o.z = f2b(v.z); o.w = f2b(v.w);
    ((ushort4*)a.dst[s])[idx] = o;
}

// ---------------------------------------------------------------- bf16 MFMA GEMM
// 256x256 tile, BK=64, 512 threads (8 waves, 2M x 4N), 8-phase schedule with
// counted vmcnt (T3+T4) + setprio (T5). C(MxN) = A(MxK) @ B^T (B stored NxK).
//
// LDS: [buf][A|B][kk] = 8 planes of 16 KiB (256 rows x 32 cols bf16) = 128 KiB.
// Staging unit = 1 plane = 2 x global_load_lds(16B)/thread, LINEAR LDS dest;
// global k-chunk pre-swizzled gq = q ^ ((row>>1)&3); reads apply the same XOR
// -> 8 lanes per 4-bank group (balanced, conflict-free like the old kernel).
//
// Phase(mh,kk) = {4-8 ds_read_b128 | stage 1 plane | barrier | lgkmcnt(0) |
//                 setprio(1) 16 MFMA setprio(0) | counted vmcnt | barrier}.
// Pipeline: planes of tile T+1 (kk=1 halves) staged in T's phases 0-1,
// planes of tile T+2 (kk=0 halves) in T's phases 2-3. vmcnt(8) at ends of
// phases 1 and 3 keeps 2 staging units in flight across every barrier
// (never drains to 0 in steady state; epilogue drains 8->4->0).
#define EPI_BIAS 1
#define EPI_RELU 2
#define EPI_PART 8
#define EPI_OUTB 16

struct PB { ushort_t* p[4]; };

#define FENCE asm volatile("" ::: "memory")

template <int F>
__global__ __launch_bounds__(512, 2) void gemm256(const ushort_t* __restrict__ A,
                                                  const ushort_t* __restrict__ B,
                                                  const float* __restrict__ bias,
                                                  PB pb,
                                                  ushort_t* __restrict__ outb,
                                                  int M, int N, int Kc, int ld) {
    __shared__ __align__(16) ushort_t lds[8 * 8192];   // 128 KiB
    const int t = threadIdx.x;

    // XCD-aware swizzle (ny == 16 for all shapes here; grid total % 8 == 0)
    const int nx = gridDim.x, ny = gridDim.y, nz = gridDim.z;
    const int lid = blockIdx.x + nx * (blockIdx.y + ny * blockIdx.z);
    const int xcd = lid & 7, slot = lid >> 3;
    const int n_i = slot % nx;
    const int rest = slot / nx;
    const int z = rest % nz;
    const int m_i = xcd * (ny >> 3) + rest / nz;

    const int n0 = n_i * 256, m0 = m_i * 256, k0 = z * Kc;
    const int lane = t & 63, w = t >> 6;
    const int wr = w >> 2, wc = w & 3;            // wave tile: 128 rows x 64 cols
    const int r16 = lane & 15, kq = lane >> 4;
    const int NT = Kc >> 6;                        // K-tiles of 64 (NT >= 2)

    f32x4_t acc[8][4] = {};

    // staging: thread t covers plane chunks c = t and c = t + 512
    const int srow = t >> 2;                       // 0..127 (chunk2: +128)
    const int gq = (t & 3) ^ ((t >> 3) & 3);       // swizzled global k-chunk
    const ushort_t* ag = A + (size_t)(m0 + srow) * ld + gq * 8 + k0;
    const ushort_t* bg = B + (size_t)(n0 + srow) * ld + gq * 8 + k0;
    const size_t step2 = (size_t)128 * ld;

    auto stage = [&](const ushort_t* g, int buf, int ab, int kk, int Tt) {
        const ushort_t* s = g + Tt * 64 + kk * 32;
        ushort_t* d = lds + ((buf * 2 + ab) * 2 + kk) * 8192 + t * 8;
        __builtin_amdgcn_global_load_lds((AS1 void*)s, (AS3 void*)d, 16, 0, 0);
        __builtin_amdgcn_global_load_lds((AS1 void*)(s + step2), (AS3 void*)(d + 4096), 16, 0, 0);
    };

    // prologue: U0(T0), U1(T0), U0(T1) = 12 loads; keep 8 in flight
    stage(ag, 0, 0, 0, 0);
    stage(bg, 0, 1, 0, 0);
    stage(ag, 0, 0, 1, 0);
    stage(bg, 0, 1, 1, 0);
    stage(ag, 1, 0, 0, 1);
    stage(bg, 1, 1, 0, 1);
    asm volatile("s_waitcnt vmcnt(8)" ::: "memory");
    FENCE;
    __builtin_amdgcn_s_barrier();
    FENCE;

    const int ccA = (kq ^ ((r16 >> 1) & 3)) * 8;   // swizzled read chunk (ushorts)
    bf16x8_t bfr[4];

    for (int T = 0; T < NT; ++T) {
        const int buf = T & 1;
        const ushort_t* pa[2]  = { lds + ((buf * 2 + 0) * 2 + 0) * 8192,
                                   lds + ((buf * 2 + 0) * 2 + 1) * 8192 };
        const ushort_t* pbB[2] = { lds + ((buf * 2 + 1) * 2 + 0) * 8192,
                                   lds + ((buf * 2 + 1) * 2 + 1) * 8192 };
#pragma unroll
        for (int ph = 0; ph < 4; ++ph) {
            const int mh = ph & 1, kk = ph >> 1;
            bf16x8_t af[4];
#pragma unroll
            for (int mi = 0; mi < 4; ++mi)
                af[mi] = *(const bf16x8_t*)(pa[kk] + (wr * 128 + mh * 64 + mi * 16 + r16) * 32 + ccA);
            if (mh == 0) {
#pragma unroll
                for (int ni = 0; ni < 4; ++ni)
                    bfr[ni] = *(const bf16x8_t*)(pbB[kk] + (wc * 64 + ni * 16 + r16) * 32 + ccA);
            }
            if (ph == 0 && T + 1 < NT) stage(ag, buf ^ 1, 0, 1, T + 1);
            if (ph == 1 && T + 1 < NT) stage(bg, buf ^ 1, 1, 1, T + 1);
            if (ph == 2 && T + 2 < NT) stage(ag, buf, 0, 0, T + 2);
            if (ph == 3 && T + 2 < NT) stage(bg, buf, 1, 0, T + 2);
            FENCE;
            __builtin_amdgcn_s_barrier();
            asm volatile("s_waitcnt lgkmcnt(0)" ::: "memory");
            __builtin_amdgcn_sched_barrier(0);
            __builtin_amdgcn_s_setprio(1);
#pragma unroll
            for (int mi = 0; mi < 4; ++mi)
#pragma unroll
                for (int ni = 0; ni < 4; ++ni)
                    acc[mh * 4 + mi][ni] = __builtin_amdgcn_mfma_f32_16x16x32_bf16(
                        af[mi], bfr[ni], acc[mh * 4 + mi][ni], 0, 0, 0);
            __builtin_amdgcn_s_setprio(0);
            if (ph == 1) {
                if (T < NT - 1) { asm volatile("s_waitcnt vmcnt(8)" ::: "memory"); }
                else            { asm volatile("s_waitcnt vmcnt(0)" ::: "memory"); }
            } else if (ph == 3) {
                if (T < NT - 2)       { asm volatile("s_waitcnt vmcnt(8)" ::: "memory"); }
                else if (T == NT - 2) { asm volatile("s_waitcnt vmcnt(4)" ::: "memory"); }
            }
            FENCE;
            __builtin_amdgcn_s_barrier();
            FENCE;
        }
    }

    ushort_t* po = (F & EPI_PART) ? pb.p[z] : outb;
#pragma unroll
    for (int a = 0; a < 8; ++a) {
#pragma unroll
        for (int ni = 0; ni < 4; ++ni) {
            const int row = m0 + wr * 128 + a * 16 + kq * 4;
            const int col = n0 + wc * 64 + ni * 16 + r16;
            float bv = (F & EPI_BIAS) ? bias[col] : 0.f;
#pragma unroll
            for (int i = 0; i < 4; ++i) {
                float v = acc[a][ni][i] + bv;
                if (F & EPI_RELU) v = fmaxf(v, 0.f);
                po[(size_t)(row + i) * N + col] = f2b(v);
            }
        }
    }
}

// ---------------------------------------------------------------- MFMA banded flash attention
// qkv: (B*S, 3072) bf16 rows [q | k | v], head h owns cols h*64..h*64+63 of each third.
__global__ __launch_bounds__(256, 4) void flash_mfma(const ushort_t* __restrict__ qkv,
                                                     ushort_t* __restrict__ attn) {
    const int S = 2048;
    const int h = blockIdx.y, bb = blockIdx.z;
    const int q0 = blockIdx.x * 64;
    const int t = threadIdx.x;
    const int w = t >> 6, lane = t & 63;
    const int r16 = lane & 15, g = lane >> 4;

    __shared__ ushort_t lk[64 * 72];
    __shared__ ushort_t lv[64 * 68];
    __shared__ ushort_t lp[4 * 16 * 72];

    const ushort_t* base = qkv + (size_t)bb * S * 3072 + (size_t)h * 64;

    bf16x8_t qa[2];
    {
        const ushort_t* qrow = base + (size_t)(q0 + 16 * w + r16) * 3072;
        qa[0] = *(const bf16x8_t*)(qrow + g * 8);
        qa[1] = *(const bf16x8_t*)(qrow + 32 + g * 8);
    }

    f32x4_t O[4] = {};
    float mrow[4] = {-1e30f, -1e30f, -1e30f, -1e30f};
    float lrow[4] = {0.f, 0.f, 0.f, 0.f};

    for (int it = 0; it < 5; ++it) {
        const int kt0 = q0 - 128 + 64 * it;
        if (kt0 < 0 || kt0 >= S) continue;

#pragma unroll
        for (int pass = 0; pass < 2; ++pass) {
            const int c = t + 256 * pass;
            const int key = c >> 3, dc = c & 7;
            const ushort_t* src = base + (size_t)(kt0 + key) * 3072 + dc * 8;
            uint4 kk = *(const uint4*)(src + 1024);
            uint4 vv = *(const uint4*)(src + 2048);
            *(uint4*)(lk + key * 72 + dc * 8) = kk;
            uint2* vd = (uint2*)(lv + key * 68 + dc * 8);
            vd[0] = make_uint2(vv.x, vv.y);
            vd[1] = make_uint2(vv.z, vv.w);
        }
        __syncthreads();

        f32x4_t s[4];
#pragma unroll
        for (int sub = 0; sub < 4; ++sub) {
            const ushort_t* krow = lk + (16 * sub + r16) * 72;
            bf16x8_t kb0 = *(const bf16x8_t*)(krow + g * 8);
            bf16x8_t kb1 = *(const bf16x8_t*)(krow + 32 + g * 8);
            f32x4_t z = {};
            z = __builtin_amdgcn_mfma_f32_16x16x32_bf16(qa[0], kb0, z, 0, 0, 0);
            z = __builtin_amdgcn_mfma_f32_16x16x32_bf16(qa[1], kb1, z, 0, 0, 0);
            s[sub] = z;
        }

        float alpha[4];
#pragma unroll
        for (int reg = 0; reg < 4; ++reg) {
            const int i = q0 + 16 * w + g * 4 + reg;
            float rm = -1e30f;
#pragma unroll
            for (int sub = 0; sub < 4; ++sub) {
                const int j = kt0 + 16 * sub + r16;
                const int d = i - j;
                const bool valid = (d <= 128) && (d >= -128);
                float v = valid ? s[sub][reg] * 0.125f : -1e30f;
                s[sub][reg] = v;
                rm = fmaxf(rm, v);
            }
#pragma unroll
            for (int msk = 1; msk < 16; msk <<= 1) rm = fmaxf(rm, __shfl_xor(rm, msk));
            const float mnew = fmaxf(mrow[reg], rm);
            alpha[reg] = __expf(mrow[reg] - mnew);
            mrow[reg] = mnew;
            float rs = 0.f;
#pragma unroll
            for (int sub = 0; sub < 4; ++sub) {
                float p = __expf(s[sub][reg] - mnew);
                s[sub][reg] = p;
                rs += p;
            }
#pragma unroll
            for (int msk = 1; msk < 16; msk <<= 1) rs += __shfl_xor(rs, msk);
            lrow[reg] = lrow[reg] * alpha[reg] + rs;
#pragma unroll
            for (int dd = 0; dd < 4; ++dd) O[dd][reg] *= alpha[reg];
        }

        ushort_t* pw = lp + w * 16 * 72;
#pragma unroll
        for (int sub = 0; sub < 4; ++sub)
#pragma unroll
            for (int reg = 0; reg < 4; ++reg)
                pw[(g * 4 + reg) * 72 + 16 * sub + r16] = f2b(s[sub][reg]);

        bf16x8_t pa0 = *(const bf16x8_t*)(pw + r16 * 72 + g * 8);
        bf16x8_t pa1 = *(const bf16x8_t*)(pw + r16 * 72 + 32 + g * 8);
        const __bf16* lvb = (const __bf16*)lv;
#pragma unroll
        for (int dd = 0; dd < 4; ++dd) {
            bf16x8_t vb0, vb1;
#pragma unroll
            for (int j = 0; j < 8; ++j) {
                vb0[j] = lvb[(g * 8 + j) * 68 + dd * 16 + r16];
                vb1[j] = lvb[(32 + g * 8 + j) * 68 + dd * 16 + r16];
            }
            O[dd] = __builtin_amdgcn_mfma_f32_16x16x32_bf16(pa0, vb0, O[dd], 0, 0, 0);
            O[dd] = __builtin_amdgcn_mfma_f32_16x16x32_bf16(pa1, vb1, O[dd], 0, 0, 0);
        }
        __syncthreads();
    }

#pragma unroll
    for (int reg = 0; reg < 4; ++reg) {
        const float inv = 1.0f / lrow[reg];
        const int i = q0 + 16 * w + g * 4 + reg;
        ushort_t* orow = attn + ((size_t)(bb * S + i)) * 1024 + (size_t)h * 64;
#pragma unroll
        for (int dd = 0; dd < 4; ++dd)
            orow[dd * 16 + r16] = f2b(O[dd][reg] * inv);
    }
}

// ---------------------------------------------------------------- LayerNorm + split-K reduce
template <int NP>
__global__ __launch_bounds__(256) void ln_red(const ushort_t* __restrict__ p0,
                                              const ushort_t* __restrict__ p1,
                                              const ushort_t* __restrict__ p2,
                                              const ushort_t* __restrict__ p3,
                                              const float* __restrict__ bias,
                                              const float* __restrict__ res,
                                              const float* __restrict__ g,
                                              const float* __restrict__ bta,
                                              float* __restrict__ outf,
                                              ushort_t* __restrict__ outb) {
    const int row = blockIdx.x;
    const int t = threadIdx.x;
    const size_t idx = (size_t)row * 256 + t;
    float4 v;
    {
        ushort4 a = ((const ushort4*)p0)[idx];
        ushort4 b = ((const ushort4*)p1)[idx];
        v.x = b2f(a.x) + b2f(b.x);
        v.y = b2f(a.y) + b2f(b.y);
        v.z = b2f(a.z) + b2f(b.z);
        v.w = b2f(a.w) + b2f(b.w);
    }
    if (NP == 4) {
        ushort4 a = ((const ushort4*)p2)[idx];
        ushort4 b = ((const ushort4*)p3)[idx];
        v.x += b2f(a.x) + b2f(b.x);
        v.y += b2f(a.y) + b2f(b.y);
        v.z += b2f(a.z) + b2f(b.z);
        v.w += b2f(a.w) + b2f(b.w);
    }
    {
        float4 bb = ((const float4*)bias)[t];
        float4 rr = ((const float4*)res)[idx];
        v.x += bb.x + rr.x; v.y += bb.y + rr.y; v.z += bb.z + rr.z; v.w += bb.w + rr.w;
    }

    float s = v.x + v.y + v.z + v.w;
    float s2 = v.x * v.x + v.y * v.y + v.z * v.z + v.w * v.w;
#pragma unroll
    for (int off = 32; off > 0; off >>= 1) {
        s += __shfl_down(s, off);
        s2 += __shfl_down(s2, off);
    }
    __shared__ float red[8];
    const int w = t >> 6, lane = t & 63;
    if (lane == 0) { red[w] = s; red[4 + w] = s2; }
    __syncthreads();
    float S1 = red[0] + red[1] + red[2] + red[3];
    float S2 = red[4] + red[5] + red[6] + red[7];
    float mean = S1 * (1.f / 1024.f);
    float var = S2 * (1.f / 1024.f) - mean * mean;
    float r = rsqrtf(var + 1e-5f);
    float4 gg = ((const float4*)g)[t];
    float4 bb = ((const float4*)bta)[t];
    float4 o;
    o.x = (v.x - mean) * r * gg.x + bb.x;
    o.y = (v.y - mean) * r * gg.y + bb.y;
    o.z = (v.z - mean) * r * gg.z + bb.z;
    o.w = (v.w - mean) * r * gg.w + bb.w;
    ((float4*)outf)[idx] = o;
    if (outb) {
        ushort4 ob;
        ob.x = f2b(o.x); ob.y = f2b(o.y); ob.z = f2b(o.z); ob.w = f2b(o.w);
        ((ushort4*)outb)[idx] = ob;
    }
}

// ---------------------------------------------------------------- launch
extern "C" void kernel_launch(void* const* d_in, const int* in_sizes, int n_in,
                              void* d_out, int out_size, void* d_ws, size_t ws_size,
                              hipStream_t stream) {
    const float* x          = (const float*)d_in[0];
    const float* in_proj_w  = (const float*)d_in[1];
    const float* in_proj_b  = (const float*)d_in[2];
    const float* out_proj_w = (const float*)d_in[3];
    const float* out_proj_b = (const float*)d_in[4];
    const float* ln1_g      = (const float*)d_in[5];
    const float* ln1_b      = (const float*)d_in[6];
    const float* w1         = (const float*)d_in[7];
    const float* b1         = (const float*)d_in[8];
    const float* w2         = (const float*)d_in[9];
    const float* b2         = (const float*)d_in[10];
    const float* ln2_g      = (const float*)d_in[11];
    const float* ln2_b      = (const float*)d_in[12];

    char* ws = (char*)d_ws;
    ushort_t* xb    = (ushort_t*)(ws + (0ull << 20));    //  8 MB: x bf16       (4096x1024)
    ushort_t* wqkvb = (ushort_t*)(ws + (8ull << 20));    //  6 MB: in_proj_w    (3072x1024)
    ushort_t* woutb = (ushort_t*)(ws + (14ull << 20));   //  2 MB: out_proj_w   (1024x1024)
    ushort_t* w1b   = (ushort_t*)(ws + (16ull << 20));   //  8 MB: w1           (4096x1024)
    ushort_t* w2b   = (ushort_t*)(ws + (24ull << 20));   //  8 MB: w2           (1024x4096)
    ushort_t* qkvb  = (ushort_t*)(ws + (32ull << 20));   // 24 MB: qkv bf16     (4096x3072)
    ushort_t* attnb = (ushort_t*)(ws + (56ull << 20));   //  8 MB: attn bf16    (4096x1024)
    float*    x2f   = (float*)(ws + (80ull << 20));      // 16 MB: x2 f32
    ushort_t* x2b   = (ushort_t*)(ws + (96ull << 20));   //  8 MB: x2 bf16
    ushort_t* hb    = (ushort_t*)(ws + (104ull << 20));  // 32 MB: relu hidden  (4096x4096)
    // bf16 split-K partials (8 MB each) in regions dead at their phase:
    ushort_t* op_p0 = (ushort_t*)(ws + (64ull << 20));   // out_proj p0
    ushort_t* op_p1 = (ushort_t*)(ws + (72ull << 20));   // out_proj p1
    ushort_t* op_p2 = (ushort_t*)(ws + (112ull << 20));  // out_proj p2 (hb not yet written)
    ushort_t* op_p3 = (ushort_t*)(ws + (120ull << 20));  // out_proj p3 (hb not yet written)
    ushort_t* f2_p0 = (ushort_t*)(ws + (0ull << 20));    // FFN2 p0 (xb dead)
    ushort_t* f2_p1 = (ushort_t*)(ws + (8ull << 20));    // FFN2 p1 (wqkvb dead)
    ushort_t* f2_p2 = (ushort_t*)(ws + (32ull << 20));   // FFN2 p2 (qkvb dead)
    ushort_t* f2_p3 = (ushort_t*)(ws + (40ull << 20));   // FFN2 p3 (qkvb dead)
    (void)in_sizes; (void)n_in; (void)out_size; (void)ws_size;

    // ---- one fused cast launch
    CastArgs ca;
    ca.src[0] = x;  ca.dst[0] = xb;
    ca.src[1] = in_proj_w;  ca.dst[1] = wqkvb;
    ca.src[2] = out_proj_w; ca.dst[2] = woutb;
    ca.src[3] = w1; ca.dst[3] = w1b;
    ca.src[4] = w2; ca.dst[4] = w2b;
    ca.cum[0] = 0;
    ca.cum[1] = 1048576;
    ca.cum[2] = 1048576 + 786432;
    ca.cum[3] = 1048576 + 786432 + 262144;
    ca.cum[4] = 1048576 + 786432 + 262144 + 1048576;
    ca.cum[5] = 1048576 + 786432 + 262144 + 1048576 + 1048576;
    cast_all<<<(ca.cum[5] + 255) / 256, 256, 0, stream>>>(ca);

    PB none = {{nullptr, nullptr, nullptr, nullptr}};

    // qkv = x @ in_proj_w.T + b   -> bf16   (grid 12x16 = 192 blocks)
    gemm256<EPI_BIAS | EPI_OUTB><<<dim3(12, 16, 1), 512, 0, stream>>>(
        xb, wqkvb, in_proj_b, none, qkvb, 4096, 3072, 1024, 1024);

    // banded MFMA flash attention -> attnb bf16
    flash_mfma<<<dim3(32, 16, 2), 256, 0, stream>>>(qkvb, attnb);

    // out_proj split-K x4 -> bf16 partials (grid 4x16x4 = 256 blocks, Kc=256)
    PB op = {{op_p0, op_p1, op_p2, op_p3}};
    gemm256<EPI_PART><<<dim3(4, 16, 4), 512, 0, stream>>>(
        attnb, woutb, nullptr, op, nullptr, 4096, 1024, 256, 1024);

    // x2 = LN1(p0..p3 + out_proj_b + x) -> f32 + bf16
    ln_red<4><<<4096, 256, 0, stream>>>(op_p0, op_p1, op_p2, op_p3,
                                        out_proj_b, x, ln1_g, ln1_b, x2f, x2b);

    // h = relu(x2 @ w1.T + b1) -> bf16   (grid 16x16 = 256 blocks)
    gemm256<EPI_BIAS | EPI_RELU | EPI_OUTB><<<dim3(16, 16, 1), 512, 0, stream>>>(
        x2b, w1b, b1, none, hb, 4096, 4096, 1024, 1024);

    // FFN2 split-K x4 -> bf16 partials (grid 4x16x4 = 256 blocks, Kc=1024)
    PB f2 = {{f2_p0, f2_p1, f2_p2, f2_p3}};
    gemm256<EPI_PART><<<dim3(4, 16, 4), 512, 0, stream>>>(
        hb, w2b, nullptr, f2, nullptr, 4096, 1024, 1024, 4096);

    // out = LN2(p0+p1+p2+p3 + b2 + x2) -> f32 d_out
    ln_red<4><<<4096, 256, 0, stream>>>(f2_p0, f2_p1, f2_p2, f2_p3,
                                        b2, x2f, ln2_g, ln2_b, (float*)d_out, nullptr);
}

// Round 2
// 306.335 us; speedup vs baseline: 1.0050x; 1.0050x over previous
//
#include <hip/hip_runtime.h>
#include <hip/hip_bf16.h>

#define AS1 __attribute__((address_space(1)))
#define AS3 __attribute__((address_space(3)))

typedef __bf16 bf16x8_t __attribute__((ext_vector_type(8)));
typedef float f32x4_t __attribute__((ext_vector_type(4)));
typedef unsigned short ushort_t;
typedef unsigned int uint_t;

static __device__ __forceinline__ ushort_t f2b(float f) {
    __hip_bfloat16 h = __float2bfloat16(f);
    return __builtin_bit_cast(unsigned short, h);
}
static __device__ __forceinline__ float b2f(ushort_t u) {
    return __uint_as_float((uint_t)u << 16);
}

// ---------------------------------------------------------------- fused casts (one launch)
struct CastArgs {
    const float* src[5];
    ushort_t* dst[5];
    int cum[6];   // prefix sums of float4-group counts
};

__global__ __launch_bounds__(256) void cast_all(CastArgs a) {
    const int i = blockIdx.x * 256 + threadIdx.x;
    if (i >= a.cum[5]) return;
    int s = 0;
#pragma unroll
    for (int k = 1; k < 5; ++k) s += (i >= a.cum[k]);
    const int idx = i - a.cum[s];
    float4 v = ((const float4*)a.src[s])[idx];
    ushort4 o;
    o.x = f2b(v.x); o.y = f2b(v.y); o.z = f2b(v.z); o.w = f2b(v.w);
    ((ushort4*)a.dst[s])[idx] = o;
}

// ---------------------------------------------------------------- bf16 MFMA GEMM
// 256x256 tile, BK=64, 512 threads (8 waves, 2M x 4N), 8-phase schedule with
// counted vmcnt (T3+T4) + setprio (T5). C(MxN) = A(MxK) @ B^T (B stored NxK).
//
// KEY (r2): all fragment loads are inline-asm ds_read_b128 so the backend's
// waitcnt pass (which cannot alias-disambiguate global_load_lds LDS-DMA from
// ds_read) does NOT insert s_waitcnt vmcnt(0) before each phase's reads --
// that auto-drain is what collapsed r1's pipeline to drain0-per-phase.
// No "memory" clobbers anywhere; ordering = volatile-asm program order +
// raw s_barrier + sched_barrier(0) after lgkmcnt(0) (rule #18).
//
// LDS planes (16 KiB each, byte base = buf*65536 + ab*32768 + kk*16384):
// row r (0..255) at byte r*64, 4 chunks of 16B, global chunk q stored at
// chunk slot q ^ ((r>>1)&3). Read addr: base + r*64 + (kq^((r16>>1)&3))*16.
#define EPI_BIAS 1
#define EPI_RELU 2
#define EPI_PART 8
#define EPI_OUTB 16

struct PB { ushort_t* p[4]; };

template <int IMM>
static __device__ __forceinline__ bf16x8_t dsr(uint_t a) {
    bf16x8_t r;
    asm volatile("ds_read_b128 %0, %1 offset:%c2" : "=v"(r) : "v"(a), "i"(IMM));
    return r;
}

#define PH(mh, kk, STG, VMW)                                                          \
  {                                                                                   \
    af[0] = dsr<16384*(kk) + 4096*(mh) + 0>(rA);                                      \
    af[1] = dsr<16384*(kk) + 4096*(mh) + 1024>(rA);                                   \
    af[2] = dsr<16384*(kk) + 4096*(mh) + 2048>(rA);                                   \
    af[3] = dsr<16384*(kk) + 4096*(mh) + 3072>(rA);                                   \
    if ((mh) == 0) {                                                                  \
      bfr[0] = dsr<32768 + 16384*(kk) + 0>(rB);                                       \
      bfr[1] = dsr<32768 + 16384*(kk) + 1024>(rB);                                    \
      bfr[2] = dsr<32768 + 16384*(kk) + 2048>(rB);                                    \
      bfr[3] = dsr<32768 + 16384*(kk) + 3072>(rB);                                    \
    }                                                                                 \
    STG;                                                                              \
    __builtin_amdgcn_s_barrier();                                                     \
    asm volatile("s_waitcnt lgkmcnt(0)");                                             \
    __builtin_amdgcn_sched_barrier(0);                                                \
    __builtin_amdgcn_s_setprio(1);                                                    \
    _Pragma("unroll")                                                                 \
    for (int mi = 0; mi < 4; ++mi)                                                    \
      _Pragma("unroll")                                                               \
      for (int ni = 0; ni < 4; ++ni)                                                  \
        acc[(mh)*4 + mi][ni] = __builtin_amdgcn_mfma_f32_16x16x32_bf16(               \
            af[mi], bfr[ni], acc[(mh)*4 + mi][ni], 0, 0, 0);                          \
    __builtin_amdgcn_s_setprio(0);                                                    \
    VMW;                                                                              \
    __builtin_amdgcn_s_barrier();                                                     \
  }

template <int F>
__global__ __launch_bounds__(512, 2) void gemm256(const ushort_t* __restrict__ A,
                                                  const ushort_t* __restrict__ B,
                                                  const float* __restrict__ bias,
                                                  PB pb,
                                                  ushort_t* __restrict__ outb,
                                                  int M, int N, int Kc, int ld) {
    __shared__ __align__(16) ushort_t lds[8 * 8192];   // 128 KiB
    const int t = threadIdx.x;

    // XCD-aware swizzle (grid total % 8 == 0, ny % 8 == 0)
    const int nx = gridDim.x, ny = gridDim.y, nz = gridDim.z;
    const int lid = blockIdx.x + nx * (blockIdx.y + ny * blockIdx.z);
    const int xcd = lid & 7, slot = lid >> 3;
    const int n_i = slot % nx;
    const int rest = slot / nx;
    const int z = rest % nz;
    const int m_i = xcd * (ny >> 3) + rest / nz;

    const int n0 = n_i * 256, m0 = m_i * 256, k0 = z * Kc;
    const int lane = t & 63, w = t >> 6;
    const int wr = w >> 2, wc = w & 3;            // wave tile: 128 rows x 64 cols
    const int r16 = lane & 15, kq = lane >> 4;
    const int NT = Kc >> 6;                        // K-tiles of 64 (NT >= 2)

    f32x4_t acc[8][4] = {};

    // staging: thread t covers plane chunks c = t and c = t + 512
    const int srow = t >> 2;                       // 0..127 (chunk2: +128)
    const int gq = (t & 3) ^ ((t >> 3) & 3);       // swizzled global k-chunk
    const ushort_t* ag = A + (size_t)(m0 + srow) * ld + gq * 8 + k0;
    const ushort_t* bg = B + (size_t)(n0 + srow) * ld + gq * 8 + k0;
    const size_t step2 = (size_t)128 * ld;

    auto stage = [&](const ushort_t* g, int buf, int ab, int kk, int Tt) {
        const ushort_t* s = g + Tt * 64 + kk * 32;
        ushort_t* d = lds + ((buf * 2 + ab) * 2 + kk) * 8192 + t * 8;
        __builtin_amdgcn_global_load_lds((AS1 void*)s, (AS3 void*)d, 16, 0, 0);
        __builtin_amdgcn_global_load_lds((AS1 void*)(s + step2), (AS3 void*)(d + 4096), 16, 0, 0);
    };

    // prologue: A/B kk0+kk1 of T0, A/B kk0 of T1 = 12 loads; oldest 4 complete
    stage(ag, 0, 0, 0, 0);
    stage(bg, 0, 1, 0, 0);
    stage(ag, 0, 0, 1, 0);
    stage(bg, 0, 1, 1, 0);
    stage(ag, 1, 0, 0, 1);
    stage(bg, 1, 1, 0, 1);
    asm volatile("s_waitcnt vmcnt(8)");
    __builtin_amdgcn_s_barrier();

    // per-lane LDS read base addresses (bytes)
    const uint_t chunk = (uint_t)((kq ^ ((r16 >> 1) & 3)) * 16);
    const uint_t regA = (uint_t)((wr * 128 + r16) * 64) + chunk;
    const uint_t regB = (uint_t)((wc * 64 + r16) * 64) + chunk;

    bf16x8_t af[4], bfr[4];

    for (int T = 0; T < NT; ++T) {
        const int buf = T & 1;
        const uint_t rA = regA + (uint_t)(buf << 16);
        const uint_t rB = regB + (uint_t)(buf << 16);
        PH(0, 0, { if (T + 1 < NT) stage(ag, buf ^ 1, 0, 1, T + 1); }, {});
        PH(1, 0, { if (T + 1 < NT) stage(bg, buf ^ 1, 1, 1, T + 1); },
                 { if (T < NT - 1) { asm volatile("s_waitcnt vmcnt(8)"); }
                   else            { asm volatile("s_waitcnt vmcnt(0)"); } });
        PH(0, 1, { if (T + 2 < NT) stage(ag, buf, 0, 0, T + 2); }, {});
        PH(1, 1, { if (T + 2 < NT) stage(bg, buf, 1, 0, T + 2); },
                 { if (T < NT - 2)       { asm volatile("s_waitcnt vmcnt(8)"); }
                   else if (T == NT - 2) { asm volatile("s_waitcnt vmcnt(4)"); } });
    }

    ushort_t* po = (F & EPI_PART) ? pb.p[z] : outb;
#pragma unroll
    for (int a = 0; a < 8; ++a) {
#pragma unroll
        for (int ni = 0; ni < 4; ++ni) {
            const int row = m0 + wr * 128 + a * 16 + kq * 4;
            const int col = n0 + wc * 64 + ni * 16 + r16;
            float bv = (F & EPI_BIAS) ? bias[col] : 0.f;
#pragma unroll
            for (int i = 0; i < 4; ++i) {
                float v = acc[a][ni][i] + bv;
                if (F & EPI_RELU) v = fmaxf(v, 0.f);
                po[(size_t)(row + i) * N + col] = f2b(v);
            }
        }
    }
}

// ---------------------------------------------------------------- MFMA banded flash attention
// qkv: (B*S, 3072) bf16 rows [q | k | v], head h owns cols h*64..h*64+63 of each third.
__global__ __launch_bounds__(256, 4) void flash_mfma(const ushort_t* __restrict__ qkv,
                                                     ushort_t* __restrict__ attn) {
    const int S = 2048;
    const int h = blockIdx.y, bb = blockIdx.z;
    const int q0 = blockIdx.x * 64;
    const int t = threadIdx.x;
    const int w = t >> 6, lane = t & 63;
    const int r16 = lane & 15, g = lane >> 4;

    __shared__ ushort_t lk[64 * 72];
    __shared__ ushort_t lv[64 * 68];
    __shared__ ushort_t lp[4 * 16 * 72];

    const ushort_t* base = qkv + (size_t)bb * S * 3072 + (size_t)h * 64;

    bf16x8_t qa[2];
    {
        const ushort_t* qrow = base + (size_t)(q0 + 16 * w + r16) * 3072;
        qa[0] = *(const bf16x8_t*)(qrow + g * 8);
        qa[1] = *(const bf16x8_t*)(qrow + 32 + g * 8);
    }

    f32x4_t O[4] = {};
    float mrow[4] = {-1e30f, -1e30f, -1e30f, -1e30f};
    float lrow[4] = {0.f, 0.f, 0.f, 0.f};

    for (int it = 0; it < 5; ++it) {
        const int kt0 = q0 - 128 + 64 * it;
        if (kt0 < 0 || kt0 >= S) continue;

#pragma unroll
        for (int pass = 0; pass < 2; ++pass) {
            const int c = t + 256 * pass;
            const int key = c >> 3, dc = c & 7;
            const ushort_t* src = base + (size_t)(kt0 + key) * 3072 + dc * 8;
            uint4 kk = *(const uint4*)(src + 1024);
            uint4 vv = *(const uint4*)(src + 2048);
            *(uint4*)(lk + key * 72 + dc * 8) = kk;
            uint2* vd = (uint2*)(lv + key * 68 + dc * 8);
            vd[0] = make_uint2(vv.x, vv.y);
            vd[1] = make_uint2(vv.z, vv.w);
        }
        __syncthreads();

        f32x4_t s[4];
#pragma unroll
        for (int sub = 0; sub < 4; ++sub) {
            const ushort_t* krow = lk + (16 * sub + r16) * 72;
            bf16x8_t kb0 = *(const bf16x8_t*)(krow + g * 8);
            bf16x8_t kb1 = *(const bf16x8_t*)(krow + 32 + g * 8);
            f32x4_t z = {};
            z = __builtin_amdgcn_mfma_f32_16x16x32_bf16(qa[0], kb0, z, 0, 0, 0);
            z = __builtin_amdgcn_mfma_f32_16x16x32_bf16(qa[1], kb1, z, 0, 0, 0);
            s[sub] = z;
        }

        float alpha[4];
#pragma unroll
        for (int reg = 0; reg < 4; ++reg) {
            const int i = q0 + 16 * w + g * 4 + reg;
            float rm = -1e30f;
#pragma unroll
            for (int sub = 0; sub < 4; ++sub) {
                const int j = kt0 + 16 * sub + r16;
                const int d = i - j;
                const bool valid = (d <= 128) && (d >= -128);
                float v = valid ? s[sub][reg] * 0.125f : -1e30f;
                s[sub][reg] = v;
                rm = fmaxf(rm, v);
            }
#pragma unroll
            for (int msk = 1; msk < 16; msk <<= 1) rm = fmaxf(rm, __shfl_xor(rm, msk));
            const float mnew = fmaxf(mrow[reg], rm);
            alpha[reg] = __expf(mrow[reg] - mnew);
            mrow[reg] = mnew;
            float rs = 0.f;
#pragma unroll
            for (int sub = 0; sub < 4; ++sub) {
                float p = __expf(s[sub][reg] - mnew);
                s[sub][reg] = p;
                rs += p;
            }
#pragma unroll
            for (int msk = 1; msk < 16; msk <<= 1) rs += __shfl_xor(rs, msk);
            lrow[reg] = lrow[reg] * alpha[reg] + rs;
#pragma unroll
            for (int dd = 0; dd < 4; ++dd) O[dd][reg] *= alpha[reg];
        }

        ushort_t* pw = lp + w * 16 * 72;
#pragma unroll
        for (int sub = 0; sub < 4; ++sub)
#pragma unroll
            for (int reg = 0; reg < 4; ++reg)
                pw[(g * 4 + reg) * 72 + 16 * sub + r16] = f2b(s[sub][reg]);

        bf16x8_t pa0 = *(const bf16x8_t*)(pw + r16 * 72 + g * 8);
        bf16x8_t pa1 = *(const bf16x8_t*)(pw + r16 * 72 + 32 + g * 8);
        const __bf16* lvb = (const __bf16*)lv;
#pragma unroll
        for (int dd = 0; dd < 4; ++dd) {
            bf16x8_t vb0, vb1;
#pragma unroll
            for (int j = 0; j < 8; ++j) {
                vb0[j] = lvb[(g * 8 + j) * 68 + dd * 16 + r16];
                vb1[j] = lvb[(32 + g * 8 + j) * 68 + dd * 16 + r16];
            }
            O[dd] = __builtin_amdgcn_mfma_f32_16x16x32_bf16(pa0, vb0, O[dd], 0, 0, 0);
            O[dd] = __builtin_amdgcn_mfma_f32_16x16x32_bf16(pa1, vb1, O[dd], 0, 0, 0);
        }
        __syncthreads();
    }

#pragma unroll
    for (int reg = 0; reg < 4; ++reg) {
        const float inv = 1.0f / lrow[reg];
        const int i = q0 + 16 * w + g * 4 + reg;
        ushort_t* orow = attn + ((size_t)(bb * S + i)) * 1024 + (size_t)h * 64;
#pragma unroll
        for (int dd = 0; dd < 4; ++dd)
            orow[dd * 16 + r16] = f2b(O[dd][reg] * inv);
    }
}

// ---------------------------------------------------------------- LayerNorm + split-K reduce
template <int NP>
__global__ __launch_bounds__(256) void ln_red(const ushort_t* __restrict__ p0,
                                              const ushort_t* __restrict__ p1,
                                              const ushort_t* __restrict__ p2,
                                              const ushort_t* __restrict__ p3,
                                              const float* __restrict__ bias,
                                              const float* __restrict__ res,
                                              const float* __restrict__ g,
                                              const float* __restrict__ bta,
                                              float* __restrict__ outf,
                                              ushort_t* __restrict__ outb) {
    const int row = blockIdx.x;
    const int t = threadIdx.x;
    const size_t idx = (size_t)row * 256 + t;
    float4 v;
    {
        ushort4 a = ((const ushort4*)p0)[idx];
        ushort4 b = ((const ushort4*)p1)[idx];
        v.x = b2f(a.x) + b2f(b.x);
        v.y = b2f(a.y) + b2f(b.y);
        v.z = b2f(a.z) + b2f(b.z);
        v.w = b2f(a.w) + b2f(b.w);
    }
    if (NP == 4) {
        ushort4 a = ((const ushort4*)p2)[idx];
        ushort4 b = ((const ushort4*)p3)[idx];
        v.x += b2f(a.x) + b2f(b.x);
        v.y += b2f(a.y) + b2f(b.y);
        v.z += b2f(a.z) + b2f(b.z);
        v.w += b2f(a.w) + b2f(b.w);
    }
    {
        float4 bb = ((const float4*)bias)[t];
        float4 rr = ((const float4*)res)[idx];
        v.x += bb.x + rr.x; v.y += bb.y + rr.y; v.z += bb.z + rr.z; v.w += bb.w + rr.w;
    }

    float s = v.x + v.y + v.z + v.w;
    float s2 = v.x * v.x + v.y * v.y + v.z * v.z + v.w * v.w;
#pragma unroll
    for (int off = 32; off > 0; off >>= 1) {
        s += __shfl_down(s, off);
        s2 += __shfl_down(s2, off);
    }
    __shared__ float red[8];
    const int w = t >> 6, lane = t & 63;
    if (lane == 0) { red[w] = s; red[4 + w] = s2; }
    __syncthreads();
    float S1 = red[0] + red[1] + red[2] + red[3];
    float S2 = red[4] + red[5] + red[6] + red[7];
    float mean = S1 * (1.f / 1024.f);
    float var = S2 * (1.f / 1024.f) - mean * mean;
    float r = rsqrtf(var + 1e-5f);
    float4 gg = ((const float4*)g)[t];
    float4 bb = ((const float4*)bta)[t];
    float4 o;
    o.x = (v.x - mean) * r * gg.x + bb.x;
    o.y = (v.y - mean) * r * gg.y + bb.y;
    o.z = (v.z - mean) * r * gg.z + bb.z;
    o.w = (v.w - mean) * r * gg.w + bb.w;
    ((float4*)outf)[idx] = o;
    if (outb) {
        ushort4 ob;
        ob.x = f2b(o.x); ob.y = f2b(o.y); ob.z = f2b(o.z); ob.w = f2b(o.w);
        ((ushort4*)outb)[idx] = ob;
    }
}

// ---------------------------------------------------------------- launch
extern "C" void kernel_launch(void* const* d_in, const int* in_sizes, int n_in,
                              void* d_out, int out_size, void* d_ws, size_t ws_size,
                              hipStream_t stream) {
    const float* x          = (const float*)d_in[0];
    const float* in_proj_w  = (const float*)d_in[1];
    const float* in_proj_b  = (const float*)d_in[2];
    const float* out_proj_w = (const float*)d_in[3];
    const float* out_proj_b = (const float*)d_in[4];
    const float* ln1_g      = (const float*)d_in[5];
    const float* ln1_b      = (const float*)d_in[6];
    const float* w1         = (const float*)d_in[7];
    const float* b1         = (const float*)d_in[8];
    const float* w2         = (const float*)d_in[9];
    const float* b2         = (const float*)d_in[10];
    const float* ln2_g      = (const float*)d_in[11];
    const float* ln2_b      = (const float*)d_in[12];

    char* ws = (char*)d_ws;
    ushort_t* xb    = (ushort_t*)(ws + (0ull << 20));    //  8 MB: x bf16       (4096x1024)
    ushort_t* wqkvb = (ushort_t*)(ws + (8ull << 20));    //  6 MB: in_proj_w    (3072x1024)
    ushort_t* woutb = (ushort_t*)(ws + (14ull << 20));   //  2 MB: out_proj_w   (1024x1024)
    ushort_t* w1b   = (ushort_t*)(ws + (16ull << 20));   //  8 MB: w1           (4096x1024)
    ushort_t* w2b   = (ushort_t*)(ws + (24ull << 20));   //  8 MB: w2           (1024x4096)
    ushort_t* qkvb  = (ushort_t*)(ws + (32ull << 20));   // 24 MB: qkv bf16     (4096x3072)
    ushort_t* attnb = (ushort_t*)(ws + (56ull << 20));   //  8 MB: attn bf16    (4096x1024)
    float*    x2f   = (float*)(ws + (80ull << 20));      // 16 MB: x2 f32
    ushort_t* x2b   = (ushort_t*)(ws + (96ull << 20));   //  8 MB: x2 bf16
    ushort_t* hb    = (ushort_t*)(ws + (104ull << 20));  // 32 MB: relu hidden  (4096x4096)
    // bf16 split-K partials (8 MB each) in regions dead at their phase:
    ushort_t* op_p0 = (ushort_t*)(ws + (64ull << 20));   // out_proj p0
    ushort_t* op_p1 = (ushort_t*)(ws + (72ull << 20));   // out_proj p1
    ushort_t* op_p2 = (ushort_t*)(ws + (112ull << 20));  // out_proj p2 (hb not yet written)
    ushort_t* op_p3 = (ushort_t*)(ws + (120ull << 20));  // out_proj p3 (hb not yet written)
    ushort_t* f2_p0 = (ushort_t*)(ws + (0ull << 20));    // FFN2 p0 (xb dead)
    ushort_t* f2_p1 = (ushort_t*)(ws + (8ull << 20));    // FFN2 p1 (wqkvb dead)
    ushort_t* f2_p2 = (ushort_t*)(ws + (32ull << 20));   // FFN2 p2 (qkvb dead)
    ushort_t* f2_p3 = (ushort_t*)(ws + (40ull << 20));   // FFN2 p3 (qkvb dead)
    (void)in_sizes; (void)n_in; (void)out_size; (void)ws_size;

    // ---- one fused cast launch
    CastArgs ca;
    ca.src[0] = x;  ca.dst[0] = xb;
    ca.src[1] = in_proj_w;  ca.dst[1] = wqkvb;
    ca.src[2] = out_proj_w; ca.dst[2] = woutb;
    ca.src[3] = w1; ca.dst[3] = w1b;
    ca.src[4] = w2; ca.dst[4] = w2b;
    ca.cum[0] = 0;
    ca.cum[1] = 1048576;
    ca.cum[2] = 1048576 + 786432;
    ca.cum[3] = 1048576 + 786432 + 262144;
    ca.cum[4] = 1048576 + 786432 + 262144 + 1048576;
    ca.cum[5] = 1048576 + 786432 + 262144 + 1048576 + 1048576;
    cast_all<<<(ca.cum[5] + 255) / 256, 256, 0, stream>>>(ca);

    PB none = {{nullptr, nullptr, nullptr, nullptr}};

    // qkv = x @ in_proj_w.T + b   -> bf16   (grid 12x16 = 192 blocks)
    gemm256<EPI_BIAS | EPI_OUTB><<<dim3(12, 16, 1), 512, 0, stream>>>(
        xb, wqkvb, in_proj_b, none, qkvb, 4096, 3072, 1024, 1024);

    // banded MFMA flash attention -> attnb bf16
    flash_mfma<<<dim3(32, 16, 2), 256, 0, stream>>>(qkvb, attnb);

    // out_proj split-K x4 -> bf16 partials (grid 4x16x4 = 256 blocks, Kc=256)
    PB op = {{op_p0, op_p1, op_p2, op_p3}};
    gemm256<EPI_PART><<<dim3(4, 16, 4), 512, 0, stream>>>(
        attnb, woutb, nullptr, op, nullptr, 4096, 1024, 256, 1024);

    // x2 = LN1(p0..p3 + out_proj_b + x) -> f32 + bf16
    ln_red<4><<<4096, 256, 0, stream>>>(op_p0, op_p1, op_p2, op_p3,
                                        out_proj_b, x, ln1_g, ln1_b, x2f, x2b);

    // h = relu(x2 @ w1.T + b1) -> bf16   (grid 16x16 = 256 blocks)
    gemm256<EPI_BIAS | EPI_RELU | EPI_OUTB><<<dim3(16, 16, 1), 512, 0, stream>>>(
        x2b, w1b, b1, none, hb, 4096, 4096, 1024, 1024);

    // FFN2 split-K x4 -> bf16 partials (grid 4x16x4 = 256 blocks, Kc=1024)
    PB f2 = {{f2_p0, f2_p1, f2_p2, f2_p3}};
    gemm256<EPI_PART><<<dim3(4, 16, 4), 512, 0, stream>>>(
        hb, w2b, nullptr, f2, nullptr, 4096, 1024, 1024, 4096);

    // out = LN2(p0+p1+p2+p3 + b2 + x2) -> f32 d_out
    ln_red<4><<<4096, 256, 0, stream>>>(f2_p0, f2_p1, f2_p2, f2_p3,
                                        b2, x2f, ln2_g, ln2_b, (float*)d_out, nullptr);
}